// Round 1
// baseline (1325.080 us; speedup 1.0000x reference)
//
#include <hip/hip_runtime.h>

// ---------------------------------------------------------------------------
// LlamaDecoderLayer forward on MI355X (gfx950).
// B=4, L=1024, D=2048, H=16, I=8192, DH=128.
// Outputs (f32): out (B,L,D) then attn (B,H,L,L), concatenated in d_out.
// ---------------------------------------------------------------------------

typedef __bf16 bf16;
typedef __bf16 bf16x8 __attribute__((ext_vector_type(8)));
typedef __bf16 bf16x4 __attribute__((ext_vector_type(4)));
typedef float  f32x4  __attribute__((ext_vector_type(4)));

constexpr int   kB  = 4;
constexpr int   kL  = 1024;
constexpr int   kD  = 2048;
constexpr int   kH  = 16;
constexpr int   kI  = 8192;
constexpr int   kDH = 128;
constexpr float kEps = 1e-6f;
constexpr float kScoreScale = 0.08838834764831845f; // 1/sqrt(128)

typedef __attribute__((address_space(1))) void gvoid_t;
typedef __attribute__((address_space(3))) void lvoid_t;

// async global->LDS, 16B per lane; LDS dest = firstlane(base)+lane*16
__device__ __forceinline__ void gload_lds16(const void* g, void* l) {
  __builtin_amdgcn_global_load_lds((gvoid_t*)g, (lvoid_t*)l, 16, 0, 0);
}

// ---------------------------------------------------------------------------
// f32 -> bf16 cast (vectorized). n must be a multiple of 4.
// ---------------------------------------------------------------------------
__global__ __launch_bounds__(256) void cast_f32_bf16_kernel(
    const float* __restrict__ x, bf16* __restrict__ y, long n) {
  long i = ((long)blockIdx.x * 256 + threadIdx.x) * 4;
  long stride = (long)gridDim.x * 256 * 4;
  for (; i < n; i += stride) {
    const float4 v = *reinterpret_cast<const float4*>(x + i);
    bf16x4 o;
    o[0] = (bf16)v.x; o[1] = (bf16)v.y; o[2] = (bf16)v.z; o[3] = (bf16)v.w;
    *reinterpret_cast<bf16x4*>(y + i) = o;
  }
}

// ---------------------------------------------------------------------------
// RMSNorm: one block per row of D=2048 f32; writes bf16.
// ---------------------------------------------------------------------------
__global__ __launch_bounds__(256) void rmsnorm_kernel(
    const float* __restrict__ x, const float* __restrict__ w,
    bf16* __restrict__ out) {
  const long row = blockIdx.x;
  const float* xr = x + row * (long)kD;
  bf16* orow = out + row * (long)kD;
  const int t = threadIdx.x;

  float4 v0 = *(const float4*)(xr + t * 8);
  float4 v1 = *(const float4*)(xr + t * 8 + 4);
  float ss = v0.x * v0.x + v0.y * v0.y + v0.z * v0.z + v0.w * v0.w +
             v1.x * v1.x + v1.y * v1.y + v1.z * v1.z + v1.w * v1.w;

  __shared__ float red[4];
  for (int off = 32; off > 0; off >>= 1) ss += __shfl_down(ss, off);
  if ((t & 63) == 0) red[t >> 6] = ss;
  __syncthreads();
  const float tot = red[0] + red[1] + red[2] + red[3];
  const float rs = rsqrtf(tot / (float)kD + kEps);

  float4 w0 = *(const float4*)(w + t * 8);
  float4 w1 = *(const float4*)(w + t * 8 + 4);
  bf16x8 o;
  o[0] = (bf16)(v0.x * rs * w0.x); o[1] = (bf16)(v0.y * rs * w0.y);
  o[2] = (bf16)(v0.z * rs * w0.z); o[3] = (bf16)(v0.w * rs * w0.w);
  o[4] = (bf16)(v1.x * rs * w1.x); o[5] = (bf16)(v1.y * rs * w1.y);
  o[6] = (bf16)(v1.z * rs * w1.z); o[7] = (bf16)(v1.w * rs * w1.w);
  *(bf16x8*)(orow + t * 8) = o;
}

// ---------------------------------------------------------------------------
// RoPE in-place on q and k (bf16, (B*L, H*DH) layout).
// out[i]   = x[i]*cos[i]   - x[i+64]*sin[i]        (i in [0,64) per head)
// out[i+64]= x[i+64]*cos[i+64] + x[i]*sin[i+64]
// ---------------------------------------------------------------------------
__global__ __launch_bounds__(256) void rope_kernel(
    bf16* __restrict__ q, bf16* __restrict__ k,
    const float* __restrict__ cosb, const float* __restrict__ sinb) {
  const long row = blockIdx.x;  // b*L + l
  const float* cr = cosb + row * (long)kDH;
  const float* sr = sinb + row * (long)kDH;
  bf16* qr = q + row * (long)kD;
  bf16* kr = k + row * (long)kD;
  const int t = threadIdx.x;
#pragma unroll
  for (int it = 0; it < 4; ++it) {
    const int p = it * 256 + t;  // 0..1023 pair index
    const int h = p >> 6, i = p & 63;
    const int i0 = h * kDH + i, i1 = i0 + 64;
    const float c0 = cr[i], s0 = sr[i], c1 = cr[i + 64], s1 = sr[i + 64];
    const float q0 = (float)qr[i0], q1 = (float)qr[i1];
    qr[i0] = (bf16)(q0 * c0 - q1 * s0);
    qr[i1] = (bf16)(q1 * c1 + q0 * s1);
    const float k0 = (float)kr[i0], k1 = (float)kr[i1];
    kr[i0] = (bf16)(k0 * c0 - k1 * s0);
    kr[i1] = (bf16)(k1 * c1 + k0 * s1);
  }
}

// ---------------------------------------------------------------------------
// v (B,L,H,DH) -> vT (B,H,DH,L)   (bf16)
// ---------------------------------------------------------------------------
__global__ __launch_bounds__(256) void transpose_v_kernel(
    const bf16* __restrict__ vb, bf16* __restrict__ vT) {
  __shared__ bf16 tile[32][33];
  const int z = blockIdx.z, b = z / kH, h = z % kH;
  const bf16* src = vb + (long)b * kL * kD + h * kDH;  // [l][d], stride D
  bf16* dst = vT + (long)z * kDH * kL;                 // [d][l], stride L
  const int l0 = blockIdx.x * 32, d0 = blockIdx.y * 32;
  const int tx = threadIdx.x & 31, ty = threadIdx.x >> 5;
  for (int r = ty; r < 32; r += 8)
    tile[r][tx] = src[(long)(l0 + r) * kD + d0 + tx];
  __syncthreads();
  for (int r = ty; r < 32; r += 8)
    dst[(long)(d0 + r) * kL + l0 + tx] = tile[tx][r];
}

// ---------------------------------------------------------------------------
// Row softmax over L=1024 f32, in-place (d_out attn region).
// ---------------------------------------------------------------------------
__global__ __launch_bounds__(256) void softmax_kernel(float* __restrict__ attn) {
  const long row = blockIdx.x;
  float* r = attn + row * (long)kL;
  const int t = threadIdx.x;
  float4 v = *(float4*)(r + t * 4);

  __shared__ float red[4];
  float m = fmaxf(fmaxf(v.x, v.y), fmaxf(v.z, v.w));
  for (int off = 32; off > 0; off >>= 1) m = fmaxf(m, __shfl_down(m, off));
  if ((t & 63) == 0) red[t >> 6] = m;
  __syncthreads();
  m = fmaxf(fmaxf(red[0], red[1]), fmaxf(red[2], red[3]));

  v.x = expf(v.x - m); v.y = expf(v.y - m);
  v.z = expf(v.z - m); v.w = expf(v.w - m);
  float s = v.x + v.y + v.z + v.w;
  __syncthreads();  // red reuse hazard
  for (int off = 32; off > 0; off >>= 1) s += __shfl_down(s, off);
  if ((t & 63) == 0) red[t >> 6] = s;
  __syncthreads();
  s = red[0] + red[1] + red[2] + red[3];
  const float inv = 1.0f / s;
  v.x *= inv; v.y *= inv; v.z *= inv; v.w *= inv;
  *(float4*)(r + t * 4) = v;
}

// ---------------------------------------------------------------------------
// GEMM: C[M][N] = epi( scale * (A[M][K] * W[N][K]^T) )
// 128x128 tile, BK=32, 256 threads (4 waves, 2x2 wave grid, 64x64 each),
// mfma_f32_16x16x32_bf16. A optionally f32 (converted while staging).
// Batch z: ptr += (z/Hdiv)*s?o + (z%Hdiv)*s?i.
// EPI: 0 none, 1 add f32 E, 2 scale+add f32 E (mask), 3 silu(E_bf16)*acc,
//      4 acc + C (read-modify-write on C, f32).
// ---------------------------------------------------------------------------
enum { EPI_NONE = 0, EPI_ADD = 1, EPI_MASK = 2, EPI_SILU = 3, EPI_OUTADD = 4 };

template <typename OutT, int EPI, bool AF32>
__global__ __launch_bounds__(256) void gemm_bt_kernel(
    const void* __restrict__ Ap, long sAo, long sAi, int lda,
    const bf16* __restrict__ Bp, long sBo, long sBi, int ldb,
    OutT* Cp, long sCo, long sCi, int ldc,
    const void* Ep, long sEo, long sEi, int lde,
    float scale, int Hdiv, int M, int N, int K) {
  const int z = blockIdx.z;
  const int zo = z / Hdiv, zi = z % Hdiv;

  const bf16* A = (const bf16*)Ap;
  const float* Af = (const float*)Ap;
  if constexpr (AF32) Af += zo * sAo + zi * sAi;
  else                A  += zo * sAo + zi * sAi;
  const bf16* Bw = Bp + zo * sBo + zi * sBi;
  OutT* C = Cp + zo * sCo + zi * sCi;

  __shared__ __align__(16) bf16 lsA[128 * 32];
  __shared__ __align__(16) bf16 lsB[128 * 32];

  const int t = threadIdx.x;
  const int m0 = blockIdx.y * 128, n0 = blockIdx.x * 128;
  const int wave = t >> 6, lane = t & 63;
  const int wm = (wave >> 1) * 64, wn = (wave & 1) * 64;
  const int lr = lane & 15, lg = lane >> 4;

  f32x4 acc[4][4] = {};

  for (int k0 = 0; k0 < K; k0 += 32) {
    __syncthreads();  // previous iter's fragment reads done before restage
#pragma unroll
    for (int c = 0; c < 2; ++c) {
      const int flat = (c * 256 + t) * 8;
      const int row = flat >> 5, col = flat & 31;
      if constexpr (AF32) {
        const float* src = Af + (long)(m0 + row) * lda + k0 + col;
        const float4 u0 = *(const float4*)src;
        const float4 u1 = *(const float4*)(src + 4);
        bf16x8 wv;
        wv[0] = (bf16)u0.x; wv[1] = (bf16)u0.y; wv[2] = (bf16)u0.z; wv[3] = (bf16)u0.w;
        wv[4] = (bf16)u1.x; wv[5] = (bf16)u1.y; wv[6] = (bf16)u1.z; wv[7] = (bf16)u1.w;
        *(bf16x8*)&lsA[flat] = wv;
      } else {
        gload_lds16(A + (long)(m0 + row) * lda + k0 + col, &lsA[flat]);
      }
      gload_lds16(Bw + (long)(n0 + row) * ldb + k0 + col, &lsB[flat]);
    }
    __syncthreads();  // drains vmcnt+lgkmcnt before barrier

    bf16x8 af[4], bfr[4];
#pragma unroll
    for (int i = 0; i < 4; ++i) {
      af[i]  = *(const bf16x8*)&lsA[(wm + i * 16 + lr) * 32 + lg * 8];
      bfr[i] = *(const bf16x8*)&lsB[(wn + i * 16 + lr) * 32 + lg * 8];
    }
#pragma unroll
    for (int i = 0; i < 4; ++i)
#pragma unroll
      for (int j = 0; j < 4; ++j)
        acc[i][j] = __builtin_amdgcn_mfma_f32_16x16x32_bf16(af[i], bfr[j],
                                                            acc[i][j], 0, 0, 0);
  }

  // epilogue: lane holds C[wm+i*16+lg*4+r][wn+j*16+lr] in acc[i][j][r]
  const float* Ef = (const float*)Ep;
  const bf16* Eb = (const bf16*)Ep;
  long ebase = 0;
  if constexpr (EPI == EPI_ADD || EPI == EPI_MASK || EPI == EPI_SILU)
    ebase = zo * sEo + zi * sEi;
#pragma unroll
  for (int i = 0; i < 4; ++i) {
#pragma unroll
    for (int j = 0; j < 4; ++j) {
      const int col = n0 + wn + j * 16 + lr;
#pragma unroll
      for (int r = 0; r < 4; ++r) {
        const int rowi = m0 + wm + i * 16 + lg * 4 + r;
        float val = acc[i][j][r] * scale;
        const long idx = (long)rowi * ldc + col;
        const long eidx = ebase + (long)rowi * lde + col;
        if constexpr (EPI == EPI_ADD || EPI == EPI_MASK) val += Ef[eidx];
        if constexpr (EPI == EPI_SILU) {
          const float g = (float)Eb[eidx];
          val = (g / (1.0f + expf(-g))) * val;
        }
        if constexpr (EPI == EPI_OUTADD) val += (float)((float*)Cp)[zo * sCo + zi * sCi + idx];
        C[idx] = (OutT)val;
      }
    }
  }
}

// ---------------------------------------------------------------------------
// Host launcher
// ---------------------------------------------------------------------------
extern "C" void kernel_launch(void* const* d_in, const int* in_sizes, int n_in,
                              void* d_out, int out_size, void* d_ws,
                              size_t ws_size, hipStream_t stream) {
  (void)in_sizes; (void)n_in; (void)out_size; (void)ws_size;

  const float* hidden = (const float*)d_in[0];
  const float* mask   = (const float*)d_in[1];
  const float* cosb   = (const float*)d_in[2];
  const float* sinb   = (const float*)d_in[3];
  const float* q_w    = (const float*)d_in[4];
  const float* k_w    = (const float*)d_in[5];
  const float* v_w    = (const float*)d_in[6];
  const float* o_w    = (const float*)d_in[7];
  const float* gate_w = (const float*)d_in[8];
  const float* up_w   = (const float*)d_in[9];
  const float* down_w = (const float*)d_in[10];
  const float* ln1    = (const float*)d_in[11];
  const float* ln2    = (const float*)d_in[12];

  float* out  = (float*)d_out;                        // (B,L,D) = h1 then final
  float* attn = out + (long)kB * kL * kD;             // (B,H,L,L)

  // workspace layout (bf16 elements), ~201 MB total
  bf16* wsb = (bf16*)d_ws;
  long off = 0;
  bf16* WQ  = wsb + off; off += (long)kD * kD;
  bf16* WK  = wsb + off; off += (long)kD * kD;
  bf16* WV  = wsb + off; off += (long)kD * kD;
  bf16* WO  = wsb + off; off += (long)kD * kD;
  bf16* WBIG = wsb + off; off += (long)kI * kD;       // shared: gate/up/down JIT
  bf16* HBF = wsb + off; off += (long)kB * kL * kD;   // h (ln1), later ctx
  bf16* QB  = wsb + off; off += (long)kB * kL * kD;   // q, later h2
  bf16* KB  = wsb + off; off += (long)kB * kL * kD;   // k
  bf16* VT  = wsb + off; off += (long)kB * kL * kD;   // v transposed (B,H,DH,L)
  bf16* GBUF = wsb + off; off += (long)kB * kL * kI;  // v (head), gate, mlp

  const long DD = (long)kD * kD;     // 4.19M
  const long ID = (long)kI * kD;     // 16.78M
  const int  ML = kB * kL;           // 4096 rows

  // 1. cast attention weights
  cast_f32_bf16_kernel<<<dim3((int)(DD / 1024)), 256, 0, stream>>>(q_w, WQ, DD);
  cast_f32_bf16_kernel<<<dim3((int)(DD / 1024)), 256, 0, stream>>>(k_w, WK, DD);
  cast_f32_bf16_kernel<<<dim3((int)(DD / 1024)), 256, 0, stream>>>(v_w, WV, DD);
  cast_f32_bf16_kernel<<<dim3((int)(DD / 1024)), 256, 0, stream>>>(o_w, WO, DD);

  // 2. rmsnorm1: hidden -> HBF (bf16)
  rmsnorm_kernel<<<ML, 256, 0, stream>>>(hidden, ln1, HBF);

  // 3-5. q,k,v projections (4096x2048x2048)
  const dim3 gProj(kD / 128, ML / 128, 1);
  gemm_bt_kernel<bf16, EPI_NONE, false><<<gProj, 256, 0, stream>>>(
      HBF, 0, 0, kD, WQ, 0, 0, kD, QB, 0, 0, kD,
      nullptr, 0, 0, 0, 1.0f, 1, ML, kD, kD);
  gemm_bt_kernel<bf16, EPI_NONE, false><<<gProj, 256, 0, stream>>>(
      HBF, 0, 0, kD, WK, 0, 0, kD, KB, 0, 0, kD,
      nullptr, 0, 0, 0, 1.0f, 1, ML, kD, kD);
  gemm_bt_kernel<bf16, EPI_NONE, false><<<gProj, 256, 0, stream>>>(
      HBF, 0, 0, kD, WV, 0, 0, kD, GBUF, 0, 0, kD,
      nullptr, 0, 0, 0, 1.0f, 1, ML, kD, kD);

  // 6. RoPE in-place on q,k
  rope_kernel<<<ML, 256, 0, stream>>>(QB, KB, cosb, sinb);

  // 7. v -> vT (B,H,DH,L)
  transpose_v_kernel<<<dim3(kL / 32, kDH / 32, kB * kH), 256, 0, stream>>>(GBUF, VT);

  // 8. scores = q k^T / sqrt(DH) + mask  -> d_out attn (f32). batch B*H.
  gemm_bt_kernel<float, EPI_MASK, false><<<dim3(kL / 128, kL / 128, kB * kH), 256, 0, stream>>>(
      QB, (long)kL * kD, kDH, kD,
      KB, (long)kL * kD, kDH, kD,
      attn, (long)kH * kL * kL, (long)kL * kL, kL,
      mask, (long)kL * kL, 0, kL,
      kScoreScale, kH, kL, kL, kDH);

  // 9. softmax rows in-place
  softmax_kernel<<<kB * kH * kL, 256, 0, stream>>>(attn);

  // 10. ctx = attn @ v  (A f32 converted on stage) -> HBF (bf16, (B,L,H,DH))
  gemm_bt_kernel<bf16, EPI_NONE, true><<<dim3(kDH / 128, kL / 128, kB * kH), 256, 0, stream>>>(
      attn, (long)kH * kL * kL, (long)kL * kL, kL,
      VT, (long)kH * kDH * kL, (long)kDH * kL, kL,
      HBF, (long)kL * kD, kDH, kD,
      nullptr, 0, 0, 0, 1.0f, kH, kL, kDH, kL);

  // 11. h1 = hidden + ctx @ o_w^T  -> d_out out region (f32)
  gemm_bt_kernel<float, EPI_ADD, false><<<gProj, 256, 0, stream>>>(
      HBF, 0, 0, kD, WO, 0, 0, kD, out, 0, 0, kD,
      hidden, 0, 0, kD, 1.0f, 1, ML, kD, kD);

  // 12. rmsnorm2: h1 -> QB (h2, bf16)
  rmsnorm_kernel<<<ML, 256, 0, stream>>>(out, ln2, QB);

  // 13. gate = h2 @ gate_w^T -> GBUF (bf16, 4096x8192)
  cast_f32_bf16_kernel<<<dim3((int)(ID / 1024)), 256, 0, stream>>>(gate_w, WBIG, ID);
  const dim3 gMlp(kI / 128, ML / 128, 1);
  gemm_bt_kernel<bf16, EPI_NONE, false><<<gMlp, 256, 0, stream>>>(
      QB, 0, 0, kD, WBIG, 0, 0, kD, GBUF, 0, 0, kI,
      nullptr, 0, 0, 0, 1.0f, 1, ML, kI, kD);

  // 14. mlp = silu(gate) * (h2 @ up_w^T) -> GBUF in-place
  cast_f32_bf16_kernel<<<dim3((int)(ID / 1024)), 256, 0, stream>>>(up_w, WBIG, ID);
  gemm_bt_kernel<bf16, EPI_SILU, false><<<gMlp, 256, 0, stream>>>(
      QB, 0, 0, kD, WBIG, 0, 0, kD, GBUF, 0, 0, kI,
      GBUF, 0, 0, kI, 1.0f, 1, ML, kI, kD);

  // 15. out = h1 + mlp @ down_w^T  (h1 already in d_out)
  cast_f32_bf16_kernel<<<dim3((int)(ID / 1024)), 256, 0, stream>>>(down_w, WBIG, ID);
  gemm_bt_kernel<float, EPI_OUTADD, false><<<gProj, 256, 0, stream>>>(
      GBUF, 0, 0, kI, WBIG, 0, 0, kI, out, 0, 0, kD,
      nullptr, 0, 0, 0, 1.0f, 1, ML, kD, kI);
}